// Round 17
// baseline (114.522 us; speedup 1.0000x reference)
//
#include <hip/hip_runtime.h>
#include <math.h>

#define P 7
#define SCALE 0.125f
#define BB 4
#define CC 256
#define HH 128
#define WW 128
#define KK 512
#define NBIN 49
#define GPB 13            // bin-groups per ROI (4 bins each, 13*4 >= 49)
#define NXCD 8

#define TRANS_BLOCKS 4096   // (HH*WW/64) * (CC/64) * BB
#define MASK_BLOCKS  4096   // KK*HH rows / 16 waves per block

__device__ __forceinline__ unsigned short f32_to_bf16_rne(float f) {
    unsigned int u = __float_as_uint(f);
    u += 0x7FFFu + ((u >> 16) & 1u);
    return (unsigned short)(u >> 16);
}

// Order-preserving bf16 -> u16 key. key 0 reserved = "empty/masked".
__device__ __forceinline__ unsigned short bf16_key(unsigned short b) {
    return (b & 0x8000u) ? (unsigned short)(~b) : (unsigned short)(b | 0x8000u);
}

__device__ __forceinline__ unsigned int pkmax_u16(unsigned int a, unsigned int b) {
    unsigned int d;
    asm("v_pk_max_u16 %0, %1, %2" : "=v"(d) : "v"(a), "v"(b));
    return d;
}

// ---- Fused prep: transpose+convert, mask->bitmask; block 0 sorts + geo ----
__global__ __launch_bounds__(1024) void prep_fused(
    const float* __restrict__ in, const float* __restrict__ masks,
    const float* __restrict__ rois,
    unsigned short* __restrict__ out, unsigned long long* __restrict__ mbits,
    unsigned int* __restrict__ kb, unsigned short* __restrict__ rowb,
    unsigned short* __restrict__ colb)
{
    __shared__ float tile[64][65];    // tile[channel][pixel]
    __shared__ int skey[KK];          // block 0 only (sort)
    const int bid = blockIdx.x;
    const int tid = threadIdx.x;

    if (bid < TRANS_BLOCKS) {
        const int p0 = (bid & 255) * 64;        // pixel tile
        const int c0 = ((bid >> 8) & 3) * 64;   // channel tile
        const int b  = bid >> 10;               // batch
        const int tx = tid & 63;
        const int ty = tid >> 6;                // 0..15

        const float* src = in + (size_t)b * CC * (HH * WW);
#pragma unroll
        for (int j = 0; j < 64; j += 16)
            tile[ty + j][tx] =
                __builtin_nontemporal_load(&src[(size_t)(c0 + ty + j) * (HH * WW) + p0 + tx]);
        __syncthreads();

        unsigned int* dst = (unsigned int*)(out + (size_t)b * (HH * WW) * CC);
#pragma unroll
        for (int i = 0; i < 2; ++i) {
            const int flat = i * 1024 + tid;
            const int px = flat >> 5;
            const int cp = flat & 31;
            const unsigned int lo = bf16_key(f32_to_bf16_rne(tile[cp * 2][px]));
            const unsigned int hi = bf16_key(f32_to_bf16_rne(tile[cp * 2 + 1][px]));
            dst[((size_t)(p0 + px) * CC + c0) / 2 + cp] = lo | (hi << 16);
        }

        if (bid == 0) {
            // sort 512 ROIs by (batch, start-row) + emit geometry records;
            // block 0 runs first so this hides under the other ~8K blocks
            __syncthreads();
            if (tid < KK) {
                const float* r = rois + (size_t)tid * 5;
                const int rb = (int)r[0];
                int rsh = (int)rintf(r[2] * SCALE);
                rsh = min(max(rsh, 0), HH - 1);
                skey[tid] = rb * HH + rsh;
            }
            __syncthreads();
            if (tid < KK) {
                const int mykey = skey[tid];
                int pos = 0;
                for (int j = 0; j < KK; ++j) {
                    const int kj = skey[j];
                    pos += (kj < mykey) || (kj == mykey && j < tid);
                }
                const float* r = rois + (size_t)tid * 5;
                const int b  = (int)r[0];
                const int sw = (int)rintf(r[1] * SCALE);
                const int sh = (int)rintf(r[2] * SCALE);
                const int ew = (int)rintf(r[3] * SCALE);
                const int eh = (int)rintf(r[4] * SCALE);
                const int roi_w = max(ew - sw + 1, 1);
                const int roi_h = max(eh - sh + 1, 1);
                kb[pos] = (unsigned int)tid | ((unsigned int)b << 16);
#pragma unroll
                for (int j = 0; j < P; ++j) {
                    const int hs = min(max((j * roi_h) / P + sh, 0), HH);
                    const int he = min(max(((j + 1) * roi_h + P - 1) / P + sh, 0), HH);
                    const int ws = min(max((j * roi_w) / P + sw, 0), WW);
                    const int we = min(max(((j + 1) * roi_w + P - 1) / P + sw, 0), WW);
                    rowb[(pos << 3) + j] = (unsigned short)(hs | (he << 8));
                    colb[(pos << 3) + j] = (unsigned short)(ws | (we << 8));
                }
            }
        }
    } else {
        const int mbid = bid - TRANS_BLOCKS;
        const int wv   = tid >> 6;              // 0..15
        const int lane = tid & 63;
        const int row  = mbid * 16 + wv;        // 0 .. KK*HH-1
        const float* mr = masks + (size_t)row * WW;
        const unsigned long long b0 = __ballot(mr[lane] > 0.5f);
        const unsigned long long b1 = __ballot(mr[64 + lane] > 0.5f);
        if (lane == 0) {
            mbits[(size_t)row * 2]     = b0;
            mbits[(size_t)row * 2 + 1] = b1;
        }
    }
}

// ---- Pool: one wave per bin; width-specialized; interleaved-group XCD map --
__global__ __launch_bounds__(256) void pool_key(
    const unsigned int* __restrict__ fbase,         // [B,HW,C/2] packed keys
    const unsigned int* __restrict__ kb,            // [K] k | b<<16 (sorted)
    const unsigned short* __restrict__ rowb,        // [K,8] hs|he<<8 (sorted)
    const unsigned short* __restrict__ colb,        // [K,8] ws|we<<8 (sorted)
    const unsigned long long* __restrict__ mbits,   // [K,H,2]
    float* __restrict__ out)                        // [K,C,P,P]
{
    // Interleaved groups-of-8: XCD x gets sorted groups {x, x+8, .., x+56}.
    // Each group = 8 spatially-adjacent ROIs (L2-tight, ~3 MB footprint);
    // groups sample the sorted order evenly (work balance across XCDs).
    const int pid = blockIdx.x;             // 0 .. KK*GPB-1
    const int x   = pid & (NXCD - 1);
    const int t   = pid >> 3;               // 0..831
    const int u   = t / (GPB * 8);          // group slot within XCD, 0..7
    const int rem = t % (GPB * 8);
    const int j   = rem / GPB;              // ROI within group, 0..7
    const int g   = rem % GPB;              // bin-group, 0..12
    const int i   = (((u << 3) + x) << 3) + j;   // sorted ROI index

    const int wv   = threadIdx.x >> 6;
    const int lane = threadIdx.x & 63;
    const int bi   = g * 4 + wv;
    if (bi >= NBIN) return;                 // wave-uniform
    const int ph = bi / P;
    const int pw = bi % P;

    const int half = lane >> 5;             // even/odd pixel of each pair
    const int c4   = (lane & 31) * 4;       // uint offset: 8 channels

    // prologue: independent small loads of precomputed records (L2-hot)
    const unsigned int kbv = kb[i];
    const int k = kbv & 0xFFFF;
    const int b = (kbv >> 16) & 0xFF;
    const unsigned int rb = rowb[(i << 3) + ph];
    const unsigned int cb = colb[(i << 3) + pw];
    const int hs = rb & 0xFF, he = (rb >> 8) & 0xFF;
    const int wl = cb & 0xFF, wr = (cb >> 8) & 0xFF;

    const unsigned int boff = (unsigned int)b * (HH * WW * (CC / 2));
    const unsigned long long* mrow = mbits + (size_t)k * (HH * 2);

    unsigned int a0 = 0, a1 = 0, a2 = 0, a3 = 0;   // packed key accumulators

    const int bw = wr - wl;

    // one row-chunk: NP pair-loads (exactly ceil(bw/2)), masked pkmax
#define ROW_CHUNK(W0, BR, NP) do {                                             \
        unsigned long long v;                                                  \
        const int s = (W0);                                                    \
        if (s >= 64)      v = hi >> (s - 64);                                  \
        else if (s == 0)  v = lo;                                              \
        else              v = (lo >> s) | (hi << (64 - s));                    \
        unsigned int chunk = (unsigned int)v & 0xFFu;                          \
        const int n = (BR) - s;                                                \
        chunk &= (n >= 8) ? 0xFFu : ((1u << n) - 1u);                          \
        const unsigned int rowoff = boff + (unsigned int)h * (WW * (CC / 2));  \
        if (NP >= 1) {                                                         \
            const unsigned int wc = (unsigned int)min(s + 0 + half, (BR) - 1); \
            const uint4 kv = *(const uint4*)(fbase + rowoff + wc * (CC / 2) + c4); \
            const unsigned int m = 0u - ((chunk >> (0 + half)) & 1u);          \
            a0 = pkmax_u16(a0, kv.x & m); a1 = pkmax_u16(a1, kv.y & m);        \
            a2 = pkmax_u16(a2, kv.z & m); a3 = pkmax_u16(a3, kv.w & m);        \
        }                                                                      \
        if (NP >= 2) {                                                         \
            const unsigned int wc = (unsigned int)min(s + 2 + half, (BR) - 1); \
            const uint4 kv = *(const uint4*)(fbase + rowoff + wc * (CC / 2) + c4); \
            const unsigned int m = 0u - ((chunk >> (2 + half)) & 1u);          \
            a0 = pkmax_u16(a0, kv.x & m); a1 = pkmax_u16(a1, kv.y & m);        \
            a2 = pkmax_u16(a2, kv.z & m); a3 = pkmax_u16(a3, kv.w & m);        \
        }                                                                      \
        if (NP >= 3) {                                                         \
            const unsigned int wc = (unsigned int)min(s + 4 + half, (BR) - 1); \
            const uint4 kv = *(const uint4*)(fbase + rowoff + wc * (CC / 2) + c4); \
            const unsigned int m = 0u - ((chunk >> (4 + half)) & 1u);          \
            a0 = pkmax_u16(a0, kv.x & m); a1 = pkmax_u16(a1, kv.y & m);        \
            a2 = pkmax_u16(a2, kv.z & m); a3 = pkmax_u16(a3, kv.w & m);        \
        }                                                                      \
        if (NP >= 4) {                                                         \
            const unsigned int wc = (unsigned int)min(s + 6 + half, (BR) - 1); \
            const uint4 kv = *(const uint4*)(fbase + rowoff + wc * (CC / 2) + c4); \
            const unsigned int m = 0u - ((chunk >> (6 + half)) & 1u);          \
            a0 = pkmax_u16(a0, kv.x & m); a1 = pkmax_u16(a1, kv.y & m);        \
            a2 = pkmax_u16(a2, kv.z & m); a3 = pkmax_u16(a3, kv.w & m);        \
        }                                                                      \
    } while (0)

#define NARROW_LOOP(NP)                                                        \
    _Pragma("unroll 4")                                                        \
    for (int h = hs; h < he; ++h) {                                            \
        const unsigned long long lo = mrow[2 * h];                             \
        const unsigned long long hi = mrow[2 * h + 1];                         \
        ROW_CHUNK(wl, wr, NP);                                                 \
    }

    if (bw > 0 && he > hs) {
        if (bw <= 8) {
            // common case: exact load count, branch chosen once per wave
            const int npair = (bw + 1) >> 1;    // 1..4
            switch (npair) {
                case 1: NARROW_LOOP(1); break;
                case 2: NARROW_LOOP(2); break;
                case 3: NARROW_LOOP(3); break;
                default: NARROW_LOOP(4); break;
            }
        } else {
            // wide bins: generic multi-chunk path (full 4-load chunks)
#pragma unroll 2
            for (int h = hs; h < he; ++h) {
                const unsigned long long lo = mrow[2 * h];
                const unsigned long long hi = mrow[2 * h + 1];
                for (int w0 = wl; w0 < wr; w0 += 8) {
                    ROW_CHUNK(w0, wr, 4);
                }
            }
        }
    }
#undef NARROW_LOOP
#undef ROW_CHUNK

    // combine pixel-halves (lane i <-> i+32 hold same channels)
    a0 = pkmax_u16(a0, (unsigned int)__shfl_xor((int)a0, 32, 64));
    a1 = pkmax_u16(a1, (unsigned int)__shfl_xor((int)a1, 32, 64));
    a2 = pkmax_u16(a2, (unsigned int)__shfl_xor((int)a2, 32, 64));
    a3 = pkmax_u16(a3, (unsigned int)__shfl_xor((int)a3, 32, 64));

    if (half == 0) {
        const unsigned int acc[4] = {a0, a1, a2, a3};
        float* o = out + ((size_t)k * CC + (size_t)c4 * 2) * NBIN + ph * P + pw;
#pragma unroll
        for (int j2 = 0; j2 < 8; ++j2) {
            const unsigned int d = acc[j2 >> 1];
            const unsigned int key = (j2 & 1) ? (d >> 16) : (d & 0xFFFFu);
            float r;
            if (key == 0u) {
                r = 0.0f;                       // empty / fully-masked bin
            } else {
                const unsigned int bbits =
                    (key & 0x8000u) ? (key ^ 0x8000u) : (~key & 0xFFFFu);
                r = __uint_as_float(bbits << 16);
            }
            o[(size_t)j2 * NBIN] = r;
        }
    }
}

// ---------- Fallback (NCHW direct, correctness-only path) ----------
__global__ __launch_bounds__(256) void ROIPool_nchw_kernel(
    const float* __restrict__ inputs, const float* __restrict__ rois,
    const float* __restrict__ masks, float* __restrict__ out)
{
    const int k  = blockIdx.x;
    const int ph = blockIdx.y;
    const int c  = threadIdx.x;

    const float* roi = rois + k * 5;
    const int b  = (int)roi[0];
    const int sw = (int)rintf(roi[1] * SCALE);
    const int sh = (int)rintf(roi[2] * SCALE);
    const int ew = (int)rintf(roi[3] * SCALE);
    const int eh = (int)rintf(roi[4] * SCALE);
    const int roi_w = max(ew - sw + 1, 1);
    const int roi_h = max(eh - sh + 1, 1);

    const int hs = min(max((ph * roi_h) / P + sh, 0), HH);
    const int he = min(max(((ph + 1) * roi_h + P - 1) / P + sh, 0), HH);

    int wsb[P], web[P];
#pragma unroll
    for (int pw = 0; pw < P; ++pw) {
        wsb[pw] = min(max((pw * roi_w) / P + sw, 0), WW);
        web[pw] = min(max(((pw + 1) * roi_w + P - 1) / P + sw, 0), WW);
    }

    const float* f = inputs + ((size_t)b * CC + c) * (HH * WW);
    const float* m = masks  + (size_t)k * (HH * WW);

    float vmax[P];
#pragma unroll
    for (int pw = 0; pw < P; ++pw) vmax[pw] = -INFINITY;

    for (int h = hs; h < he; ++h) {
        const float* frow = f + h * WW;
        const float* mrow = m + h * WW;
#pragma unroll
        for (int pw = 0; pw < P; ++pw) {
            float v = vmax[pw];
            for (int w = wsb[pw]; w < web[pw]; ++w)
                if (mrow[w] > 0.5f) v = fmaxf(v, frow[w]);
            vmax[pw] = v;
        }
    }

    float* o = out + (((size_t)k * CC + c) * P + ph) * P;
#pragma unroll
    for (int pw = 0; pw < P; ++pw) {
        const float v = vmax[pw];
        o[pw] = isinf(v) ? 0.0f : v;
    }
}

extern "C" void kernel_launch(void* const* d_in, const int* in_sizes, int n_in,
                              void* d_out, int out_size, void* d_ws, size_t ws_size,
                              hipStream_t stream) {
    const float* inputs = (const float*)d_in[0];
    const float* rois   = (const float*)d_in[1];
    const float* masks  = (const float*)d_in[2];
    float* out = (float*)d_out;

    const size_t keys_bytes  = (size_t)BB * CC * HH * WW * sizeof(unsigned short); // 32 MiB
    const size_t mbits_bytes = (size_t)KK * HH * 2 * sizeof(unsigned long long);   // 1 MiB
    const size_t kb_bytes    = (size_t)KK * sizeof(unsigned int);                  // 2 KiB
    const size_t rb_bytes    = (size_t)KK * 8 * sizeof(unsigned short);            // 8 KiB
    const size_t cb_bytes    = (size_t)KK * 8 * sizeof(unsigned short);            // 8 KiB

    if (ws_size >= keys_bytes + mbits_bytes + kb_bytes + rb_bytes + cb_bytes) {
        char* p = (char*)d_ws;
        unsigned short* fT = (unsigned short*)p;              p += keys_bytes;
        unsigned long long* mb = (unsigned long long*)p;      p += mbits_bytes;
        unsigned int* kb = (unsigned int*)p;                  p += kb_bytes;
        unsigned short* rowb = (unsigned short*)p;            p += rb_bytes;
        unsigned short* colb = (unsigned short*)p;
        {
            dim3 grid(TRANS_BLOCKS + MASK_BLOCKS);
            dim3 block(1024);
            prep_fused<<<grid, block, 0, stream>>>(inputs, masks, rois, fT, mb,
                                                   kb, rowb, colb);
        }
        {
            dim3 grid(KK * GPB);
            dim3 block(256);
            pool_key<<<grid, block, 0, stream>>>((const unsigned int*)fT, kb,
                                                 rowb, colb, mb, out);
        }
    } else {
        dim3 grid(KK, P);
        dim3 block(CC);
        ROIPool_nchw_kernel<<<grid, block, 0, stream>>>(inputs, rois, masks, out);
    }
}

// Round 18
// 105.391 us; speedup vs baseline: 1.0866x; 1.0866x over previous
//
#include <hip/hip_runtime.h>
#include <math.h>

#define P 7
#define SCALE 0.125f
#define BB 4
#define CC 256
#define HH 128
#define WW 128
#define KK 512
#define NBIN 49
#define GPB 13            // bin-groups per ROI (4 bins each, 13*4 >= 49)
#define NXCD 8
#define RPX  (KK / NXCD)  // 64 ROIs per XCD slice

#define TRANS_BLOCKS 4096   // (HH*WW/64) * (CC/64) * BB
#define MASK_BLOCKS  4096   // KK*HH rows / 16 waves per block

__device__ __forceinline__ unsigned short f32_to_bf16_rne(float f) {
    unsigned int u = __float_as_uint(f);
    u += 0x7FFFu + ((u >> 16) & 1u);
    return (unsigned short)(u >> 16);
}

// Order-preserving bf16 -> u16 key. key 0 reserved = "empty/masked".
__device__ __forceinline__ unsigned short bf16_key(unsigned short b) {
    return (b & 0x8000u) ? (unsigned short)(~b) : (unsigned short)(b | 0x8000u);
}

__device__ __forceinline__ unsigned int pkmax_u16(unsigned int a, unsigned int b) {
    unsigned int d;
    asm("v_pk_max_u16 %0, %1, %2" : "=v"(d) : "v"(a), "v"(b));
    return d;
}

// ---- Fused prep: transpose+convert, mask->bitmask; block 0 sorts + geo ----
__global__ __launch_bounds__(1024) void prep_fused(
    const float* __restrict__ in, const float* __restrict__ masks,
    const float* __restrict__ rois,
    unsigned short* __restrict__ out, unsigned long long* __restrict__ mbits,
    unsigned int* __restrict__ kb, unsigned short* __restrict__ rowb,
    unsigned short* __restrict__ colb)
{
    __shared__ float tile[64][65];    // tile[channel][pixel]
    __shared__ int skey[KK];          // block 0 only (sort)
    const int bid = blockIdx.x;
    const int tid = threadIdx.x;

    if (bid < TRANS_BLOCKS) {
        const int p0 = (bid & 255) * 64;        // pixel tile
        const int c0 = ((bid >> 8) & 3) * 64;   // channel tile
        const int b  = bid >> 10;               // batch
        const int tx = tid & 63;
        const int ty = tid >> 6;                // 0..15

        const float* src = in + (size_t)b * CC * (HH * WW);
#pragma unroll
        for (int j = 0; j < 64; j += 16)
            tile[ty + j][tx] =
                __builtin_nontemporal_load(&src[(size_t)(c0 + ty + j) * (HH * WW) + p0 + tx]);
        __syncthreads();

        unsigned int* dst = (unsigned int*)(out + (size_t)b * (HH * WW) * CC);
#pragma unroll
        for (int i = 0; i < 2; ++i) {
            const int flat = i * 1024 + tid;
            const int px = flat >> 5;
            const int cp = flat & 31;
            const unsigned int lo = bf16_key(f32_to_bf16_rne(tile[cp * 2][px]));
            const unsigned int hi = bf16_key(f32_to_bf16_rne(tile[cp * 2 + 1][px]));
            dst[((size_t)(p0 + px) * CC + c0) / 2 + cp] = lo | (hi << 16);
        }

        if (bid == 0) {
            // sort 512 ROIs by (batch, start-row) + emit geometry records;
            // block 0 runs first so this hides under the other ~8K blocks
            __syncthreads();
            if (tid < KK) {
                const float* r = rois + (size_t)tid * 5;
                const int rb = (int)r[0];
                int rsh = (int)rintf(r[2] * SCALE);
                rsh = min(max(rsh, 0), HH - 1);
                skey[tid] = rb * HH + rsh;
            }
            __syncthreads();
            if (tid < KK) {
                const int mykey = skey[tid];
                int pos = 0;
                for (int j = 0; j < KK; ++j) {
                    const int kj = skey[j];
                    pos += (kj < mykey) || (kj == mykey && j < tid);
                }
                const float* r = rois + (size_t)tid * 5;
                const int b  = (int)r[0];
                const int sw = (int)rintf(r[1] * SCALE);
                const int sh = (int)rintf(r[2] * SCALE);
                const int ew = (int)rintf(r[3] * SCALE);
                const int eh = (int)rintf(r[4] * SCALE);
                const int roi_w = max(ew - sw + 1, 1);
                const int roi_h = max(eh - sh + 1, 1);
                kb[pos] = (unsigned int)tid | ((unsigned int)b << 16);
#pragma unroll
                for (int j = 0; j < P; ++j) {
                    const int hs = min(max((j * roi_h) / P + sh, 0), HH);
                    const int he = min(max(((j + 1) * roi_h + P - 1) / P + sh, 0), HH);
                    const int ws = min(max((j * roi_w) / P + sw, 0), WW);
                    const int we = min(max(((j + 1) * roi_w + P - 1) / P + sw, 0), WW);
                    rowb[(pos << 3) + j] = (unsigned short)(hs | (he << 8));
                    colb[(pos << 3) + j] = (unsigned short)(ws | (we << 8));
                }
            }
        }
    } else {
        const int mbid = bid - TRANS_BLOCKS;
        const int wv   = tid >> 6;              // 0..15
        const int lane = tid & 63;
        const int row  = mbid * 16 + wv;        // 0 .. KK*HH-1
        const float* mr = masks + (size_t)row * WW;
        const unsigned long long b0 = __ballot(mr[lane] > 0.5f);
        const unsigned long long b1 = __ballot(mr[64 + lane] > 0.5f);
        if (lane == 0) {
            mbits[(size_t)row * 2]     = b0;
            mbits[(size_t)row * 2 + 1] = b1;
        }
    }
}

// ---- Pool: one wave per bin; width-specialized; contiguous XCD slices ----
__global__ __launch_bounds__(256) void pool_key(
    const unsigned int* __restrict__ fbase,         // [B,HW,C/2] packed keys
    const unsigned int* __restrict__ kb,            // [K] k | b<<16 (sorted)
    const unsigned short* __restrict__ rowb,        // [K,8] hs|he<<8 (sorted)
    const unsigned short* __restrict__ colb,        // [K,8] ws|we<<8 (sorted)
    const unsigned long long* __restrict__ mbits,   // [K,H,2]
    float* __restrict__ out)                        // [K,C,P,P]
{
    // XCD x processes sorted-slice [x*64, x*64+64): consecutive sorted ROIs
    // overlap spatially, so the active window slides smoothly through L2.
    const int pid = blockIdx.x;
    const int x   = pid & (NXCD - 1);
    const int t   = pid >> 3;
    const int g   = t % GPB;
    const int q   = t / GPB;                // 0..63
    const int i   = x * RPX + q;            // sorted ROI index

    const int wv   = threadIdx.x >> 6;
    const int lane = threadIdx.x & 63;
    const int bi   = g * 4 + wv;
    if (bi >= NBIN) return;                 // wave-uniform
    const int ph = bi / P;
    const int pw = bi % P;

    const int half = lane >> 5;             // even/odd pixel of each pair
    const int c4   = (lane & 31) * 4;       // uint offset: 8 channels

    // prologue: independent small loads of precomputed records (L2-hot)
    const unsigned int kbv = kb[i];
    const int k = kbv & 0xFFFF;
    const int b = (kbv >> 16) & 0xFF;
    const unsigned int rb = rowb[(i << 3) + ph];
    const unsigned int cb = colb[(i << 3) + pw];
    const int hs = rb & 0xFF, he = (rb >> 8) & 0xFF;
    const int wl = cb & 0xFF, wr = (cb >> 8) & 0xFF;

    const unsigned int boff = (unsigned int)b * (HH * WW * (CC / 2));
    const unsigned long long* mrow = mbits + (size_t)k * (HH * 2);

    unsigned int a0 = 0, a1 = 0, a2 = 0, a3 = 0;   // packed key accumulators

    const int bw = wr - wl;

    // one row-chunk: NP pair-loads (exactly ceil(bw/2)), masked pkmax
#define ROW_CHUNK(W0, BR, NP) do {                                             \
        unsigned long long v;                                                  \
        const int s = (W0);                                                    \
        if (s >= 64)      v = hi >> (s - 64);                                  \
        else if (s == 0)  v = lo;                                              \
        else              v = (lo >> s) | (hi << (64 - s));                    \
        unsigned int chunk = (unsigned int)v & 0xFFu;                          \
        const int n = (BR) - s;                                                \
        chunk &= (n >= 8) ? 0xFFu : ((1u << n) - 1u);                          \
        const unsigned int rowoff = boff + (unsigned int)h * (WW * (CC / 2));  \
        if (NP >= 1) {                                                         \
            const unsigned int wc = (unsigned int)min(s + 0 + half, (BR) - 1); \
            const uint4 kv = *(const uint4*)(fbase + rowoff + wc * (CC / 2) + c4); \
            const unsigned int m = 0u - ((chunk >> (0 + half)) & 1u);          \
            a0 = pkmax_u16(a0, kv.x & m); a1 = pkmax_u16(a1, kv.y & m);        \
            a2 = pkmax_u16(a2, kv.z & m); a3 = pkmax_u16(a3, kv.w & m);        \
        }                                                                      \
        if (NP >= 2) {                                                         \
            const unsigned int wc = (unsigned int)min(s + 2 + half, (BR) - 1); \
            const uint4 kv = *(const uint4*)(fbase + rowoff + wc * (CC / 2) + c4); \
            const unsigned int m = 0u - ((chunk >> (2 + half)) & 1u);          \
            a0 = pkmax_u16(a0, kv.x & m); a1 = pkmax_u16(a1, kv.y & m);        \
            a2 = pkmax_u16(a2, kv.z & m); a3 = pkmax_u16(a3, kv.w & m);        \
        }                                                                      \
        if (NP >= 3) {                                                         \
            const unsigned int wc = (unsigned int)min(s + 4 + half, (BR) - 1); \
            const uint4 kv = *(const uint4*)(fbase + rowoff + wc * (CC / 2) + c4); \
            const unsigned int m = 0u - ((chunk >> (4 + half)) & 1u);          \
            a0 = pkmax_u16(a0, kv.x & m); a1 = pkmax_u16(a1, kv.y & m);        \
            a2 = pkmax_u16(a2, kv.z & m); a3 = pkmax_u16(a3, kv.w & m);        \
        }                                                                      \
        if (NP >= 4) {                                                         \
            const unsigned int wc = (unsigned int)min(s + 6 + half, (BR) - 1); \
            const uint4 kv = *(const uint4*)(fbase + rowoff + wc * (CC / 2) + c4); \
            const unsigned int m = 0u - ((chunk >> (6 + half)) & 1u);          \
            a0 = pkmax_u16(a0, kv.x & m); a1 = pkmax_u16(a1, kv.y & m);        \
            a2 = pkmax_u16(a2, kv.z & m); a3 = pkmax_u16(a3, kv.w & m);        \
        }                                                                      \
    } while (0)

#define NARROW_LOOP(NP)                                                        \
    _Pragma("unroll 4")                                                        \
    for (int h = hs; h < he; ++h) {                                            \
        const unsigned long long lo = mrow[2 * h];                             \
        const unsigned long long hi = mrow[2 * h + 1];                         \
        ROW_CHUNK(wl, wr, NP);                                                 \
    }

    if (bw > 0 && he > hs) {
        if (bw <= 8) {
            // common case: exact load count, branch chosen once per wave
            const int npair = (bw + 1) >> 1;    // 1..4
            switch (npair) {
                case 1: NARROW_LOOP(1); break;
                case 2: NARROW_LOOP(2); break;
                case 3: NARROW_LOOP(3); break;
                default: NARROW_LOOP(4); break;
            }
        } else {
            // wide bins: generic multi-chunk path (full 4-load chunks)
#pragma unroll 2
            for (int h = hs; h < he; ++h) {
                const unsigned long long lo = mrow[2 * h];
                const unsigned long long hi = mrow[2 * h + 1];
                for (int w0 = wl; w0 < wr; w0 += 8) {
                    ROW_CHUNK(w0, wr, 4);
                }
            }
        }
    }
#undef NARROW_LOOP
#undef ROW_CHUNK

    // combine pixel-halves (lane i <-> i+32 hold same channels)
    a0 = pkmax_u16(a0, (unsigned int)__shfl_xor((int)a0, 32, 64));
    a1 = pkmax_u16(a1, (unsigned int)__shfl_xor((int)a1, 32, 64));
    a2 = pkmax_u16(a2, (unsigned int)__shfl_xor((int)a2, 32, 64));
    a3 = pkmax_u16(a3, (unsigned int)__shfl_xor((int)a3, 32, 64));

    if (half == 0) {
        const unsigned int acc[4] = {a0, a1, a2, a3};
        float* o = out + ((size_t)k * CC + (size_t)c4 * 2) * NBIN + ph * P + pw;
#pragma unroll
        for (int j = 0; j < 8; ++j) {
            const unsigned int d = acc[j >> 1];
            const unsigned int key = (j & 1) ? (d >> 16) : (d & 0xFFFFu);
            float r;
            if (key == 0u) {
                r = 0.0f;                       // empty / fully-masked bin
            } else {
                const unsigned int bbits =
                    (key & 0x8000u) ? (key ^ 0x8000u) : (~key & 0xFFFFu);
                r = __uint_as_float(bbits << 16);
            }
            o[(size_t)j * NBIN] = r;
        }
    }
}

// ---------- Fallback (NCHW direct, correctness-only path) ----------
__global__ __launch_bounds__(256) void ROIPool_nchw_kernel(
    const float* __restrict__ inputs, const float* __restrict__ rois,
    const float* __restrict__ masks, float* __restrict__ out)
{
    const int k  = blockIdx.x;
    const int ph = blockIdx.y;
    const int c  = threadIdx.x;

    const float* roi = rois + k * 5;
    const int b  = (int)roi[0];
    const int sw = (int)rintf(roi[1] * SCALE);
    const int sh = (int)rintf(roi[2] * SCALE);
    const int ew = (int)rintf(roi[3] * SCALE);
    const int eh = (int)rintf(roi[4] * SCALE);
    const int roi_w = max(ew - sw + 1, 1);
    const int roi_h = max(eh - sh + 1, 1);

    const int hs = min(max((ph * roi_h) / P + sh, 0), HH);
    const int he = min(max(((ph + 1) * roi_h + P - 1) / P + sh, 0), HH);

    int wsb[P], web[P];
#pragma unroll
    for (int pw = 0; pw < P; ++pw) {
        wsb[pw] = min(max((pw * roi_w) / P + sw, 0), WW);
        web[pw] = min(max(((pw + 1) * roi_w + P - 1) / P + sw, 0), WW);
    }

    const float* f = inputs + ((size_t)b * CC + c) * (HH * WW);
    const float* m = masks  + (size_t)k * (HH * WW);

    float vmax[P];
#pragma unroll
    for (int pw = 0; pw < P; ++pw) vmax[pw] = -INFINITY;

    for (int h = hs; h < he; ++h) {
        const float* frow = f + h * WW;
        const float* mrow = m + h * WW;
#pragma unroll
        for (int pw = 0; pw < P; ++pw) {
            float v = vmax[pw];
            for (int w = wsb[pw]; w < web[pw]; ++w)
                if (mrow[w] > 0.5f) v = fmaxf(v, frow[w]);
            vmax[pw] = v;
        }
    }

    float* o = out + (((size_t)k * CC + c) * P + ph) * P;
#pragma unroll
    for (int pw = 0; pw < P; ++pw) {
        const float v = vmax[pw];
        o[pw] = isinf(v) ? 0.0f : v;
    }
}

extern "C" void kernel_launch(void* const* d_in, const int* in_sizes, int n_in,
                              void* d_out, int out_size, void* d_ws, size_t ws_size,
                              hipStream_t stream) {
    const float* inputs = (const float*)d_in[0];
    const float* rois   = (const float*)d_in[1];
    const float* masks  = (const float*)d_in[2];
    float* out = (float*)d_out;

    const size_t keys_bytes  = (size_t)BB * CC * HH * WW * sizeof(unsigned short); // 32 MiB
    const size_t mbits_bytes = (size_t)KK * HH * 2 * sizeof(unsigned long long);   // 1 MiB
    const size_t kb_bytes    = (size_t)KK * sizeof(unsigned int);                  // 2 KiB
    const size_t rb_bytes    = (size_t)KK * 8 * sizeof(unsigned short);            // 8 KiB
    const size_t cb_bytes    = (size_t)KK * 8 * sizeof(unsigned short);            // 8 KiB

    if (ws_size >= keys_bytes + mbits_bytes + kb_bytes + rb_bytes + cb_bytes) {
        char* p = (char*)d_ws;
        unsigned short* fT = (unsigned short*)p;              p += keys_bytes;
        unsigned long long* mb = (unsigned long long*)p;      p += mbits_bytes;
        unsigned int* kb = (unsigned int*)p;                  p += kb_bytes;
        unsigned short* rowb = (unsigned short*)p;            p += rb_bytes;
        unsigned short* colb = (unsigned short*)p;
        {
            dim3 grid(TRANS_BLOCKS + MASK_BLOCKS);
            dim3 block(1024);
            prep_fused<<<grid, block, 0, stream>>>(inputs, masks, rois, fT, mb,
                                                   kb, rowb, colb);
        }
        {
            dim3 grid(KK * GPB);
            dim3 block(256);
            pool_key<<<grid, block, 0, stream>>>((const unsigned int*)fT, kb,
                                                 rowb, colb, mb, out);
        }
    } else {
        dim3 grid(KK, P);
        dim3 block(CC);
        ROIPool_nchw_kernel<<<grid, block, 0, stream>>>(inputs, rois, masks, out);
    }
}